// Round 1
// baseline (94.049 us; speedup 1.0000x reference)
//
#include <hip/hip_runtime.h>
#include <hip/hip_bf16.h>

typedef __attribute__((ext_vector_type(8))) short bf16x8;
typedef __attribute__((ext_vector_type(4))) float f32x4;

constexpr int L  = 128;
constexpr int BK = 128;              // bf16 columns staged per chunk
constexpr int LDS_PITCH = BK * 2;    // 256 bytes per row

__device__ inline unsigned short f2bf(float x) {
    __hip_bfloat16 b = __float2bfloat16(x);
    return *reinterpret_cast<unsigned short*>(&b);
}

__device__ inline bf16x8 ld_frag(const char* lds, int row, int kk, int lane) {
    int byteoff = row * LDS_PITCH + (kk + 8 * (lane >> 4)) * 2;
    byteoff ^= (row & 7) << 4;       // same XOR swizzle as the write side
    return *reinterpret_cast<const bf16x8*>(lds + byteoff);
}

__global__ __launch_bounds__(256, 2)
void gram_kernel(const float* __restrict__ slots, float* __restrict__ gram,
                 int D, int nChunks) {
    __shared__ __align__(16) char lds[L * LDS_PITCH];   // 32 KB
    const int t    = threadIdx.x;
    const int wave = t >> 6;
    const int lane = t & 63;

    f32x4 acc[2][8];
#pragma unroll
    for (int r = 0; r < 2; ++r)
#pragma unroll
        for (int c = 0; c < 8; ++c) acc[r][c] = (f32x4)0.f;

    for (int chunk = blockIdx.x; chunk < nChunks; chunk += gridDim.x) {
        const size_t c0 = (size_t)chunk * BK;

        // ---- stage: 128 rows x 128 cols f32 -> bf16 LDS (swizzled) ----
        // 32 float4 per row * 128 rows = 4096 float4; 256 threads -> 16 each
#pragma unroll
        for (int q = 0; q < 16; ++q) {
            int idx  = t + 256 * q;          // 0..4095
            int row  = idx >> 5;
            int col4 = idx & 31;
            const float4 v = *reinterpret_cast<const float4*>(
                slots + (size_t)row * D + c0 + (size_t)col4 * 4);
            ushort4 h;
            h.x = f2bf(v.x); h.y = f2bf(v.y); h.z = f2bf(v.z); h.w = f2bf(v.w);
            int byteoff = row * LDS_PITCH + col4 * 8;
            byteoff ^= (row & 7) << 4;
            *reinterpret_cast<ushort4*>(lds + byteoff) = h;
        }
        __syncthreads();

        // ---- MFMA: wave w computes rows [32w, 32w+32) x all 128 cols ----
#pragma unroll
        for (int kk = 0; kk < BK; kk += 32) {
            bf16x8 a0 = ld_frag(lds, wave * 32 +      (lane & 15), kk, lane);
            bf16x8 a1 = ld_frag(lds, wave * 32 + 16 + (lane & 15), kk, lane);
#pragma unroll
            for (int c = 0; c < 8; ++c) {
                bf16x8 b = ld_frag(lds, c * 16 + (lane & 15), kk, lane);
                acc[0][c] = __builtin_amdgcn_mfma_f32_16x16x32_bf16(a0, b, acc[0][c], 0, 0, 0);
                acc[1][c] = __builtin_amdgcn_mfma_f32_16x16x32_bf16(a1, b, acc[1][c], 0, 0, 0);
            }
        }
        __syncthreads();
    }

    // ---- writeback: C/D layout col = lane&15, row = (lane>>4)*4 + reg ----
#pragma unroll
    for (int r = 0; r < 2; ++r)
#pragma unroll
        for (int c = 0; c < 8; ++c)
#pragma unroll
            for (int reg = 0; reg < 4; ++reg) {
                int grow = wave * 32 + r * 16 + (lane >> 4) * 4 + reg;
                int gcol = c * 16 + (lane & 15);
                atomicAdd(&gram[grow * L + gcol], acc[r][c][reg]);
            }
}

__global__ void zero_kernel(float* __restrict__ p, int n) {
    int i = blockIdx.x * 256 + threadIdx.x;
    if (i < n) p[i] = 0.f;
}

__global__ void finalize_kernel(const float* __restrict__ gram,
                                const float* __restrict__ temperature,
                                float* __restrict__ out) {
    __shared__ float norms[L];
    __shared__ float red[L];
    const int t = threadIdx.x;          // 0..127, one row each
    norms[t] = sqrtf(gram[t * L + t]);
    __syncthreads();

    const float invT = 1.0f / temperature[0];
    const float ni = norms[t];

    float rowsum = 0.f;
    for (int j = 0; j < L; ++j) {
        float sim = gram[t * L + j] / fmaxf(ni * norms[j], 1e-6f);
        rowsum += expf(sim * invT);
    }
    float total = 0.f;
    for (int j = t + 1; j < L; ++j) {
        float logit = (gram[t * L + j] / fmaxf(ni * norms[j], 1e-6f)) * invT;
        float e = expf(logit);
        float denom = rowsum - e;
        total += -(logit - logf(denom)) * (float)(j - t);
    }
    red[t] = total;
    __syncthreads();
    for (int s = 64; s > 0; s >>= 1) {
        if (t < s) red[t] += red[t + s];
        __syncthreads();
    }
    if (t == 0) out[0] = red[0] / ((float)(L - 1) * (float)(L - 1) * 0.5f);
}

extern "C" void kernel_launch(void* const* d_in, const int* in_sizes, int n_in,
                              void* d_out, int out_size, void* d_ws, size_t ws_size,
                              hipStream_t stream) {
    const float* slots       = (const float*)d_in[0];
    const float* temperature = (const float*)d_in[1];
    float* gram = (float*)d_ws;                     // L*L*4 = 64 KB scratch
    float* out  = (float*)d_out;

    const int D = in_sizes[0] / L;                  // 262144
    const int nChunks = D / BK;                     // 2048

    zero_kernel<<<(L * L + 255) / 256, 256, 0, stream>>>(gram, L * L);

    int grid = 512;
    if (grid > nChunks) grid = nChunks;
    gram_kernel<<<grid, 256, 0, stream>>>(slots, gram, D, nChunks);

    finalize_kernel<<<1, L, 0, stream>>>(gram, temperature, out);
}

// Round 2
// 59.992 us; speedup vs baseline: 1.5677x; 1.5677x over previous
//
#include <hip/hip_runtime.h>
#include <hip/hip_bf16.h>

typedef __attribute__((ext_vector_type(8))) short bf16x8;
typedef __attribute__((ext_vector_type(4))) float f32x4;

constexpr int L  = 128;
constexpr int BK = 128;              // bf16 columns staged per chunk
constexpr int LDS_PITCH = BK * 2;    // 256 bytes per row
constexpr int GRID = 512;            // 2 blocks/CU (64 KB LDS each)

__device__ inline bf16x8 ld_frag(const char* lds, int row, int kk, int lane) {
    int byteoff = row * LDS_PITCH + (kk + 8 * (lane >> 4)) * 2;
    byteoff ^= (row & 7) << 4;       // same XOR swizzle as the write side
    return *reinterpret_cast<const bf16x8*>(lds + byteoff);
}

__global__ __launch_bounds__(256, 2)
void gram_kernel(const float* __restrict__ slots, float* __restrict__ partial,
                 int D, int nChunks, int G) {
    __shared__ __align__(16) char lds[2][L * LDS_PITCH];   // 2 x 32 KB
    const int t    = threadIdx.x;
    const int wave = t >> 6;
    const int lane = t & 63;

    f32x4 acc[2][8];
#pragma unroll
    for (int r = 0; r < 2; ++r)
#pragma unroll
        for (int c = 0; c < 8; ++c) acc[r][c] = (f32x4)0.f;

    float4 ld[16];

    // ---- helpers (unrolled, static indices only) ----
    auto issue = [&](int chunk) {
        const size_t c0 = (size_t)chunk * BK;
#pragma unroll
        for (int q = 0; q < 16; ++q) {
            int idx  = t + 256 * q;          // 0..4095
            int row  = idx >> 5;
            int col4 = idx & 31;
            ld[q] = *reinterpret_cast<const float4*>(
                slots + (size_t)row * D + c0 + (size_t)col4 * 4);
        }
    };
    auto commit = [&](int buf) {
#pragma unroll
        for (int q = 0; q < 16; ++q) {
            int idx  = t + 256 * q;
            int row  = idx >> 5;
            int col4 = idx & 31;
            const unsigned int* f = reinterpret_cast<const unsigned int*>(&ld[q]);
            uint2 p;
            // truncate f32 -> bf16: take high 16 bits of each float, 1 v_perm per pair
            p.x = __builtin_amdgcn_perm(f[1], f[0], 0x07060302u);
            p.y = __builtin_amdgcn_perm(f[3], f[2], 0x07060302u);
            int byteoff = row * LDS_PITCH + col4 * 8;
            byteoff ^= (row & 7) << 4;
            *reinterpret_cast<uint2*>(&lds[buf][0] + byteoff) = p;
        }
    };

    // ---- prologue: stage first chunk ----
    issue(blockIdx.x);
    commit(0);
    __syncthreads();

    int k = 0;
    for (int c = blockIdx.x; c < nChunks; c += G, ++k) {
        const int nxt = c + G;
        if (nxt < nChunks) issue(nxt);           // prefetch overlaps MFMA below
        const int cur = k & 1;

#pragma unroll
        for (int kk = 0; kk < BK; kk += 32) {
            bf16x8 a0 = ld_frag(&lds[cur][0], wave * 32 +      (lane & 15), kk, lane);
            bf16x8 a1 = ld_frag(&lds[cur][0], wave * 32 + 16 + (lane & 15), kk, lane);
#pragma unroll
            for (int cc = 0; cc < 8; ++cc) {
                bf16x8 b = ld_frag(&lds[cur][0], cc * 16 + (lane & 15), kk, lane);
                acc[0][cc] = __builtin_amdgcn_mfma_f32_16x16x32_bf16(a0, b, acc[0][cc], 0, 0, 0);
                acc[1][cc] = __builtin_amdgcn_mfma_f32_16x16x32_bf16(a1, b, acc[1][cc], 0, 0, 0);
            }
        }

        if (nxt < nChunks) commit(cur ^ 1);
        __syncthreads();
    }

    // ---- coalesced partial writeout: slot = (r*8+c), addr = slot*1024 + t*4 ----
    float* pb = partial + (size_t)blockIdx.x * (L * L);
#pragma unroll
    for (int r = 0; r < 2; ++r)
#pragma unroll
        for (int c = 0; c < 8; ++c)
            *reinterpret_cast<float4*>(pb + (r * 8 + c) * 1024 + t * 4) =
                *reinterpret_cast<float4*>(&acc[r][c]);
}

__global__ void zero_kernel(float* __restrict__ p, int n) {
    int i = blockIdx.x * 256 + threadIdx.x;
    if (i < n) p[i] = 0.f;
}

// grid (16, NY); each block.y sums G/NY partials for 4096 float4 slots, atomic-combines.
__global__ void reduce_kernel(const float* __restrict__ partial, float* __restrict__ gram,
                              int G, int span) {
    const int id = blockIdx.x * 256 + threadIdx.x;   // 0..4095 float4 slot
    const int b0 = blockIdx.y * span;
    const int b1 = (b0 + span < G) ? b0 + span : G;

    float4 sum = make_float4(0.f, 0.f, 0.f, 0.f);
    for (int b = b0; b < b1; ++b) {
        const float4 v = *reinterpret_cast<const float4*>(
            partial + (size_t)b * (L * L) + (size_t)id * 4);
        sum.x += v.x; sum.y += v.y; sum.z += v.z; sum.w += v.w;
    }
    // decode slot -> (grow, gcol): flat = slot*1024 + t*4 + reg
    const int tt   = id & 255;
    const int slot = id >> 8;
    const int wave = tt >> 6, lane = tt & 63;
    const int r = slot >> 3, c = slot & 7;
    const int growb = wave * 32 + r * 16 + ((lane >> 4) << 2);
    const int gcol  = c * 16 + (lane & 15);
    atomicAdd(&gram[(growb + 0) * L + gcol], sum.x);
    atomicAdd(&gram[(growb + 1) * L + gcol], sum.y);
    atomicAdd(&gram[(growb + 2) * L + gcol], sum.z);
    atomicAdd(&gram[(growb + 3) * L + gcol], sum.w);
}

__global__ __launch_bounds__(1024, 1)
void finalize_kernel(const float* __restrict__ gram,
                     const float* __restrict__ temperature,
                     float* __restrict__ out) {
    __shared__ float g[L * L];       // 64 KB
    __shared__ float norms[L];
    __shared__ float wsum[16];
    const int t = threadIdx.x;       // 0..1023

#pragma unroll
    for (int q = 0; q < 4; ++q) {
        int i = t + 1024 * q;        // float4 index 0..4095
        *reinterpret_cast<float4*>(&g[i * 4]) =
            *reinterpret_cast<const float4*>(&gram[i * 4]);
    }
    __syncthreads();
    if (t < L) norms[t] = sqrtf(g[t * L + t]);
    __syncthreads();

    const float invT = 1.0f / temperature[0];
    const int r = t >> 3;            // row, 8 threads per row
    const int q = t & 7;
    const float ni = norms[r];

    // phase 1: full row sum of exp(sim/T)
    float ps = 0.f;
    for (int j = q; j < L; j += 8) {
        float sim = g[r * L + j] / fmaxf(ni * norms[j], 1e-6f);
        ps += __expf(sim * invT);
    }
    ps += __shfl_xor(ps, 1);
    ps += __shfl_xor(ps, 2);
    ps += __shfl_xor(ps, 4);
    const float rowsum = ps;

    // phase 2: upper-triangle weighted sum
    float tot = 0.f;
    for (int j = q; j < L; j += 8) {
        if (j > r) {
            float logit = (g[r * L + j] / fmaxf(ni * norms[j], 1e-6f)) * invT;
            float e = __expf(logit);
            tot += -(logit - __logf(rowsum - e)) * (float)(j - r);
        }
    }
#pragma unroll
    for (int s = 1; s < 64; s <<= 1) tot += __shfl_xor(tot, s);
    if ((t & 63) == 0) wsum[t >> 6] = tot;
    __syncthreads();
    if (t == 0) {
        float s = 0.f;
        for (int w = 0; w < 16; ++w) s += wsum[w];
        out[0] = s / ((float)(L - 1) * (float)(L - 1) * 0.5f);
    }
}

extern "C" void kernel_launch(void* const* d_in, const int* in_sizes, int n_in,
                              void* d_out, int out_size, void* d_ws, size_t ws_size,
                              hipStream_t stream) {
    const float* slots       = (const float*)d_in[0];
    const float* temperature = (const float*)d_in[1];
    float* out  = (float*)d_out;

    const int D = in_sizes[0] / L;                  // 262144
    const int nChunks = D / BK;                     // 2048
    int G = GRID;
    if (G > nChunks) G = nChunks;

    float* partial = (float*)d_ws;                          // G * 64 KB
    float* gram    = (float*)d_ws + (size_t)G * L * L;      // 64 KB

    zero_kernel<<<(L * L + 255) / 256, 256, 0, stream>>>(gram, L * L);
    gram_kernel<<<G, 256, 0, stream>>>(slots, partial, D, nChunks, G);

    const int NY = 8;
    dim3 rgrid(16, NY);
    reduce_kernel<<<rgrid, 256, 0, stream>>>(partial, gram, G, (G + NY - 1) / NY);

    finalize_kernel<<<1, 1024, 0, stream>>>(gram, temperature, out);
}